// Round 11
// baseline (323.344 us; speedup 1.0000x reference)
//
#include <hip/hip_runtime.h>
#include <math.h>

// ---------------------------------------------------------------------------
// GCN critic network. v11 = v10 + NONTEMPORAL hp gathers (L1 bypass).
// Model fitting r3-r10: agg time = lines / (C_eff/latency), C_eff ~= 16
// lines/CU ~= ONE divergent gather instruction -> the CU L1/TA miss path
// serializes gather instructions. All wave-level concurrency changes were
// null (depth, dual-node, 4/8-edge, bytes). The only untried lever is
// routing the gather around L1: nt-flag loads. hp lines have ~1.16x intra-CU
// reuse, so bypassing L1 loses nothing. (r5's NT regression was on csr
// streams with 8x reuse - different data.)
// ---------------------------------------------------------------------------

typedef _Float16 h8 __attribute__((ext_vector_type(8)));
typedef _Float16 half8 __attribute__((ext_vector_type(8)));

__global__ __launch_bounds__(256) void zero_kernel(int* __restrict__ degc,
                                                   float* __restrict__ psum,
                                                   unsigned int* __restrict__ pmax, int n) {
  int i = blockIdx.x * 256 + threadIdx.x;
  if (i < n) degc[i] = 0;
  if (blockIdx.x == 0 && threadIdx.x < 64) {
    psum[threadIdx.x] = 0.0f;
    pmax[threadIdx.x] = 0u;
  }
}

__global__ __launch_bounds__(256) void hist_kernel(const int* __restrict__ dst,
                                                   int* __restrict__ degc, int E) {
  int e = blockIdx.x * 256 + threadIdx.x;
  if (e < E) atomicAdd(&degc[dst[e]], 1);
}

// --- hierarchical exclusive scan of degc -> rowptr --------------------------
__global__ __launch_bounds__(256) void scanA_kernel(const int* __restrict__ deg,
                                                    int* __restrict__ bsum, int n) {
  __shared__ int sdata[256];
  int t = threadIdx.x;
  int i = blockIdx.x * 256 + t;
  sdata[t] = (i < n) ? deg[i] : 0;
  __syncthreads();
  for (int off = 128; off > 0; off >>= 1) {
    if (t < off) sdata[t] += sdata[t + off];
    __syncthreads();
  }
  if (t == 0) bsum[blockIdx.x] = sdata[0];
}

__global__ __launch_bounds__(256) void scanB_kernel(int* __restrict__ bsum, int nb) {
  __shared__ int s[256];
  int t = threadIdx.x;
  int v = (t < nb) ? bsum[t] : 0;
  s[t] = v;
  __syncthreads();
  for (int off = 1; off < 256; off <<= 1) {
    int x = (t >= off) ? s[t - off] : 0;
    __syncthreads();
    s[t] += x;
    __syncthreads();
  }
  if (t < nb) bsum[t] = s[t] - v;  // exclusive block offsets
}

// scanC: rowptr + dinv + per-bucket write cursors (bucket = node>>8)
__global__ __launch_bounds__(256) void scanC_kernel(const int* __restrict__ deg,
                                                    const int* __restrict__ bsum,
                                                    int* __restrict__ rowptr,
                                                    float* __restrict__ dinv,
                                                    int* __restrict__ bkt_cur,
                                                    int n, int e_total) {
  __shared__ int s[256];
  int t = threadIdx.x;
  int i = blockIdx.x * 256 + t;
  int v = (i < n) ? deg[i] : 0;
  s[t] = v;
  __syncthreads();
  for (int off = 1; off < 256; off <<= 1) {
    int x = (t >= off) ? s[t - off] : 0;
    __syncthreads();
    s[t] += x;
    __syncthreads();
  }
  if (i < n) {
    int excl = bsum[blockIdx.x] + s[t] - v;
    rowptr[i] = excl;
    dinv[i] = 1.0f / sqrtf((float)v + 1.0f);
    if ((i & 255) == 0) bkt_cur[i >> 8] = excl;  // bucket base in CSR coords
  }
  if (i == 0) rowptr[n] = e_total;
}

// --- binA: bucket-sort edges by dst>>8, packed (src<<8)|(dst&255) -----------
__global__ __launch_bounds__(256) void binA_kernel(const int* __restrict__ src,
                                                   const int* __restrict__ dst,
                                                   int* __restrict__ bkt_cur,
                                                   int* __restrict__ binned, int E) {
  __shared__ int hist[256];
  __shared__ int scan[256];
  __shared__ int delta[256];
  __shared__ int lcur[256];
  __shared__ int sorted[4096];
  __shared__ unsigned char bkt_of[4096];
  const int t = threadIdx.x;
  hist[t] = 0;
  __syncthreads();
  const int e0 = blockIdx.x * 4096;
  int pk[16];
  int bk[16];
#pragma unroll
  for (int i = 0; i < 16; ++i) {
    int e = e0 + t + 256 * i;  // coalesced
    if (e < E) {
      int s_ = src[e], d_ = dst[e];
      int b = d_ >> 8;
      pk[i] = (s_ << 8) | (d_ & 255);
      bk[i] = b;
      atomicAdd(&hist[b], 1);
    } else {
      bk[i] = -1;
    }
  }
  __syncthreads();
  int v = hist[t];
  scan[t] = v;
  __syncthreads();
  for (int off = 1; off < 256; off <<= 1) {
    int x = (t >= off) ? scan[t - off] : 0;
    __syncthreads();
    scan[t] += x;
    __syncthreads();
  }
  int excl = scan[t] - v;
  int g = (v > 0) ? atomicAdd(&bkt_cur[t], v) : 0;  // reserve global space
  delta[t] = g - excl;
  lcur[t] = excl;
  __syncthreads();
#pragma unroll
  for (int i = 0; i < 16; ++i) {
    if (bk[i] >= 0) {
      int p = atomicAdd(&lcur[bk[i]], 1);
      sorted[p] = pk[i];
      bkt_of[p] = (unsigned char)bk[i];
    }
  }
  __syncthreads();
  const int tot = scan[255];
  for (int i = t; i < tot; i += 256)  // coalesced run writes
    binned[delta[bkt_of[i]] + i] = sorted[i];
}

// --- binB: per-bucket CSR build (one block per 256-node bucket) -------------
__global__ __launch_bounds__(256) void binB_kernel(const int* __restrict__ rowptr,
                                                   const int* __restrict__ binned,
                                                   int* __restrict__ csr_src, int n) {
  __shared__ int lcur[256];
  const int t = threadIdx.x;
  const int base = blockIdx.x << 8;
  const int rbeg = rowptr[base];
  const int node = base + t;
  lcur[t] = (node < n) ? rowptr[node] - rbeg : 0;
  const int nend = (base + 256 < n) ? base + 256 : n;
  const int rend = rowptr[nend];
  const int cnt = rend - rbeg;
  __syncthreads();
  for (int i = t; i < cnt; i += 256) {
    int e = binned[rbeg + i];               // coalesced read
    int p = atomicAdd(&lcur[e & 255], 1);   // LDS cursor
    csr_src[rbeg + p] = e >> 8;             // scatter within 16KB window
  }
}

// --- dense matmul C[N,64] = fp16( dinv[row] * (A[N,K] @ W[K,64]) ) ----------
template <int K>
__global__ __launch_bounds__(256) void mm_kernel(const float* __restrict__ A,
                                                 const float* __restrict__ W,
                                                 const float* __restrict__ dinv,
                                                 _Float16* __restrict__ C, int nrows) {
  __shared__ float As[64 * K];
  const int t = threadIdx.x;
  const int lane = t & 63;
  const int wid = __builtin_amdgcn_readfirstlane(t >> 6);
  const int row0 = blockIdx.x * 64;

  constexpr int F4_PER_ROW = K / 4;
  constexpr int ROW_SHIFT = (K == 128) ? 5 : 4;
#pragma unroll
  for (int i = 0; i < K / 16; ++i) {
    int e4 = t + 256 * i;
    int r = e4 >> ROW_SHIFT;
    int k = (e4 & (F4_PER_ROW - 1)) * 4;
    int rc = row0 + r;
    if (rc > nrows - 1) rc = nrows - 1;
    float4 v = *(const float4*)(A + (size_t)rc * K + k);
    int s = r & 31;
    As[r * K + ((k + 0) ^ s)] = v.x;
    As[r * K + ((k + 1) ^ s)] = v.y;
    As[r * K + ((k + 2) ^ s)] = v.z;
    As[r * K + ((k + 3) ^ s)] = v.w;
  }
  __syncthreads();

  const int colbase = wid * 16;
  const float* Wc = W + colbase;
  float acc[16];
#pragma unroll
  for (int j = 0; j < 16; ++j) acc[j] = 0.0f;
  const int sw = lane & 31;
  const float* Arow = As + lane * K;

#pragma unroll 8
  for (int k = 0; k < K; ++k) {
    float a = Arow[k ^ sw];
    const float* Wk = Wc + k * 64;
#pragma unroll
    for (int j = 0; j < 16; ++j) acc[j] = fmaf(a, Wk[j], acc[j]);
  }

  int row = row0 + lane;
  if (row < nrows) {
    float dv = dinv[row];
    _Float16* Crow = C + (size_t)row * 64 + colbase;
    half8 o0, o1;
#pragma unroll
    for (int q = 0; q < 8; ++q) o0[q] = (_Float16)(dv * acc[q]);
#pragma unroll
    for (int q = 0; q < 8; ++q) o1[q] = (_Float16)(dv * acc[8 + q]);
    *(half8*)(Crow + 0) = o0;
    *(half8*)(Crow + 8) = o1;
  }
}

// --- agg v11: 8 edges per gather instruction, NT (L1-bypass) hp loads -------
__global__ __launch_bounds__(256) void agg_kernel(const _Float16* __restrict__ hp,
                                                  const int* __restrict__ rowptr,
                                                  const int* __restrict__ csr_src,
                                                  const float* __restrict__ dinv,
                                                  const float* __restrict__ bias,
                                                  float* __restrict__ out, int n) {
  const int t = threadIdx.x;
  const int lane = t & 63;
  const int g = lane >> 3;
  const int s = lane & 7;
  const int wid = __builtin_amdgcn_readfirstlane(t >> 6);
  const int node = blockIdx.x * 4 + wid;   // wave-uniform
  if (node >= n) return;
  const int rbeg = rowptr[node];           // s_load
  const int rend = rowptr[node + 1];
  const int deg = rend - rbeg;
  const int nbf = deg >> 3;
  const int rem = deg & 7;

  float a0, a1, a2, a3, a4, a5, a6, a7;
  {  // self term: counted once (slot-0 lanes only)
    h8 v = __builtin_nontemporal_load((const h8*)(hp + ((size_t)node << 6) + (s << 3)));
    float m = (g == 0) ? 1.0f : 0.0f;
    a0 = m * (float)v[0]; a1 = m * (float)v[1];
    a2 = m * (float)v[2]; a3 = m * (float)v[3];
    a4 = m * (float)v[4]; a5 = m * (float)v[5];
    a6 = m * (float)v[6]; a7 = m * (float)v[7];
  }

  int j = rbeg;
#pragma unroll 2
  for (int b = 0; b < nbf; ++b, j += 8) {
    int i0 = csr_src[j + 0], i1 = csr_src[j + 1], i2 = csr_src[j + 2], i3 = csr_src[j + 3];
    int i4 = csr_src[j + 4], i5 = csr_src[j + 5], i6 = csr_src[j + 6], i7 = csr_src[j + 7];
    int idx = (g & 4) ? ((g & 2) ? ((g & 1) ? i7 : i6) : ((g & 1) ? i5 : i4))
                      : ((g & 2) ? ((g & 1) ? i3 : i2) : ((g & 1) ? i1 : i0));
    h8 v = __builtin_nontemporal_load((const h8*)(hp + ((size_t)idx << 6) + (s << 3)));
    a0 += (float)v[0]; a1 += (float)v[1];
    a2 += (float)v[2]; a3 += (float)v[3];
    a4 += (float)v[4]; a5 += (float)v[5];
    a6 += (float)v[6]; a7 += (float)v[7];
  }
  if (rem) {
    int i0 = csr_src[j + 0];
    int i1 = (rem > 1) ? csr_src[j + 1] : i0;
    int i2 = (rem > 2) ? csr_src[j + 2] : i0;
    int i3 = (rem > 3) ? csr_src[j + 3] : i0;
    int i4 = (rem > 4) ? csr_src[j + 4] : i0;
    int i5 = (rem > 5) ? csr_src[j + 5] : i0;
    int i6 = (rem > 6) ? csr_src[j + 6] : i0;
    int idx = (g & 4) ? ((g & 2) ? ((g & 1) ? i0 : i6) : ((g & 1) ? i5 : i4))
                      : ((g & 2) ? ((g & 1) ? i3 : i2) : ((g & 1) ? i1 : i0));
    h8 v = __builtin_nontemporal_load((const h8*)(hp + ((size_t)idx << 6) + (s << 3)));
    float w = (g < rem) ? 1.0f : 0.0f;
    a0 = fmaf(w, (float)v[0], a0); a1 = fmaf(w, (float)v[1], a1);
    a2 = fmaf(w, (float)v[2], a2); a3 = fmaf(w, (float)v[3], a3);
    a4 = fmaf(w, (float)v[4], a4); a5 = fmaf(w, (float)v[5], a5);
    a6 = fmaf(w, (float)v[6], a6); a7 = fmaf(w, (float)v[7], a7);
  }

  // reduce across the 8 edge-slot groups (lanes s, s+8, ..., s+56)
  a0 += __shfl_xor(a0, 8); a0 += __shfl_xor(a0, 16); a0 += __shfl_xor(a0, 32);
  a1 += __shfl_xor(a1, 8); a1 += __shfl_xor(a1, 16); a1 += __shfl_xor(a1, 32);
  a2 += __shfl_xor(a2, 8); a2 += __shfl_xor(a2, 16); a2 += __shfl_xor(a2, 32);
  a3 += __shfl_xor(a3, 8); a3 += __shfl_xor(a3, 16); a3 += __shfl_xor(a3, 32);
  a4 += __shfl_xor(a4, 8); a4 += __shfl_xor(a4, 16); a4 += __shfl_xor(a4, 32);
  a5 += __shfl_xor(a5, 8); a5 += __shfl_xor(a5, 16); a5 += __shfl_xor(a5, 32);
  a6 += __shfl_xor(a6, 8); a6 += __shfl_xor(a6, 16); a6 += __shfl_xor(a6, 32);
  a7 += __shfl_xor(a7, 8); a7 += __shfl_xor(a7, 16); a7 += __shfl_xor(a7, 32);

  if (g == 0) {
    const float dv = dinv[node];
    const float* bp = bias + (s << 3);
    float4 b0 = *(const float4*)(bp + 0);
    float4 b1 = *(const float4*)(bp + 4);
    float4 r0, r1;
    r0.x = fmaxf(fmaf(dv, a0, b0.x), 0.0f);
    r0.y = fmaxf(fmaf(dv, a1, b0.y), 0.0f);
    r0.z = fmaxf(fmaf(dv, a2, b0.z), 0.0f);
    r0.w = fmaxf(fmaf(dv, a3, b0.w), 0.0f);
    r1.x = fmaxf(fmaf(dv, a4, b1.x), 0.0f);
    r1.y = fmaxf(fmaf(dv, a5, b1.y), 0.0f);
    r1.z = fmaxf(fmaf(dv, a6, b1.z), 0.0f);
    r1.w = fmaxf(fmaf(dv, a7, b1.w), 0.0f);
    float* op = out + ((size_t)node << 6) + (s << 3);
    *(float4*)(op + 0) = r0;
    *(float4*)(op + 4) = r1;
  }
}

// --- pooling: 256 blocks (atomic depth 256), unroll-4 independent loads -----
__global__ __launch_bounds__(256) void pool_kernel(const float* __restrict__ gbuf,
                                                   float* __restrict__ psum,
                                                   unsigned int* __restrict__ pmax, int n) {
  __shared__ float ls[4][64];
  __shared__ float lm[4][64];
  const int lane = threadIdx.x & 63;
  const int wid = threadIdx.x >> 6;
  const int stride = 256 * 4;  // wave-slots
  float s = 0.0f, m = 0.0f;    // post-relu values >= 0
  for (int base = blockIdx.x * 4 + wid; base < n; base += 4 * stride) {
#pragma unroll
    for (int k = 0; k < 4; ++k) {  // 4 independent loads in flight
      int node = base + k * stride;
      if (node < n) {
        float v = gbuf[((size_t)node << 6) + lane];
        s += v;
        m = fmaxf(m, v);
      }
    }
  }
  ls[wid][lane] = s;
  lm[wid][lane] = m;
  __syncthreads();
  if (wid == 0) {
    for (int w = 1; w < 4; ++w) {
      s += ls[w][lane];
      m = fmaxf(m, lm[w][lane]);
    }
    atomicAdd(&psum[lane], s);
    atomicMax(&pmax[lane], __float_as_uint(m));
  }
}

// --- MLP head ---------------------------------------------------------------
__global__ __launch_bounds__(64) void head_kernel(const float* __restrict__ psum,
                                                  const float* __restrict__ pmaxf,
                                                  const float* __restrict__ fw1,
                                                  const float* __restrict__ fb1,
                                                  const float* __restrict__ fw2,
                                                  const float* __restrict__ fb2,
                                                  float* __restrict__ out, float invN) {
  int lane = threadIdx.x;
  float acc = fb1[lane];
#pragma unroll 4
  for (int k = 0; k < 64; ++k)
    acc = fmaf(psum[k] * invN, fw1[k * 64 + lane], acc);
#pragma unroll 4
  for (int k = 0; k < 64; ++k)
    acc = fmaf(pmaxf[k], fw1[(64 + k) * 64 + lane], acc);
  float a = fmaxf(acc, 0.0f) * fw2[lane];
  for (int off = 32; off > 0; off >>= 1) a += __shfl_down(a, off);
  if (lane == 0) out[0] = a + fb2[0];
}

extern "C" void kernel_launch(void* const* d_in, const int* in_sizes, int n_in,
                              void* d_out, int out_size, void* d_ws, size_t ws_size,
                              hipStream_t stream) {
  const float* x   = (const float*)d_in[0];
  const int*   ei  = (const int*)d_in[1];
  const float* W1  = (const float*)d_in[2];
  const float* b1  = (const float*)d_in[3];
  const float* W2  = (const float*)d_in[4];
  const float* b2  = (const float*)d_in[5];
  const float* W3  = (const float*)d_in[6];
  const float* b3  = (const float*)d_in[7];
  const float* fw1 = (const float*)d_in[8];
  const float* fb1 = (const float*)d_in[9];
  const float* fw2 = (const float*)d_in[10];
  const float* fb2 = (const float*)d_in[11];
  float* out = (float*)d_out;

  const int N = in_sizes[0] / 128;  // 50000
  const int E = in_sizes[1] / 2;    // 800000
  const int* src = ei;
  const int* dst = ei + E;

  char* ws = (char*)d_ws;
  size_t off = 0;
  auto alloc = [&](size_t bytes) -> char* {
    char* p = ws + off;
    off = (off + bytes + 255) & ~(size_t)255;
    return p;
  };
  float*        dinv    = (float*)alloc((size_t)N * 4);
  int*          degc    = (int*)alloc((size_t)N * 4);
  int*          rowptr  = (int*)alloc((size_t)(N + 1) * 4);
  int*          bsum    = (int*)alloc(256 * 4);
  int*          bkt_cur = (int*)alloc(256 * 4);
  int*          binned  = (int*)alloc((size_t)E * 4 + 64);
  int*          csr_src = (int*)alloc((size_t)E * 4 + 64);  // pad: safe overread
  _Float16*     bufA    = (_Float16*)alloc((size_t)N * 64 * 2);
  float*        bufB    = (float*)alloc((size_t)N * 64 * 4);
  float*        psum    = (float*)alloc(64 * 4);
  unsigned int* pmax    = (unsigned int*)alloc(64 * 4);

  const int histBlk = (E + 255) / 256;
  const int scanBlk = (N + 255) / 256;   // 196 (<=256, required by scanB)
  const int mmBlk   = (N + 63) / 64;
  const int aggBlk  = (N + 3) / 4;       // 1 node per wave
  const int NB      = (N + 255) / 256;   // 196 buckets
  const int binBlk  = (E + 4095) / 4096; // 196 tiles

  zero_kernel<<<scanBlk, 256, 0, stream>>>(degc, psum, pmax, N);
  hist_kernel<<<histBlk, 256, 0, stream>>>(dst, degc, E);
  scanA_kernel<<<scanBlk, 256, 0, stream>>>(degc, bsum, N);
  scanB_kernel<<<1, 256, 0, stream>>>(bsum, scanBlk);
  scanC_kernel<<<scanBlk, 256, 0, stream>>>(degc, bsum, rowptr, dinv, bkt_cur, N, E);
  binA_kernel<<<binBlk, 256, 0, stream>>>(src, dst, bkt_cur, binned, E);
  binB_kernel<<<NB, 256, 0, stream>>>(rowptr, binned, csr_src, N);

  // layer 1
  mm_kernel<128><<<mmBlk, 256, 0, stream>>>(x, W1, dinv, bufA, N);
  agg_kernel<<<aggBlk, 256, 0, stream>>>(bufA, rowptr, csr_src, dinv, b1, bufB, N);
  // layer 2
  mm_kernel<64><<<mmBlk, 256, 0, stream>>>(bufB, W2, dinv, bufA, N);
  agg_kernel<<<aggBlk, 256, 0, stream>>>(bufA, rowptr, csr_src, dinv, b2, bufB, N);
  // layer 3
  mm_kernel<64><<<mmBlk, 256, 0, stream>>>(bufB, W3, dinv, bufA, N);
  agg_kernel<<<aggBlk, 256, 0, stream>>>(bufA, rowptr, csr_src, dinv, b3, bufB, N);

  pool_kernel<<<256, 256, 0, stream>>>(bufB, psum, pmax, N);
  head_kernel<<<1, 64, 0, stream>>>(psum, (const float*)pmax, fw1, fb1, fw2, fb2, out,
                                    1.0f / (float)N);
}

// Round 12
// 274.556 us; speedup vs baseline: 1.1777x; 1.1777x over previous
//
#include <hip/hip_runtime.h>
#include <math.h>

// ---------------------------------------------------------------------------
// GCN critic network. v12 = v10 (plain-load agg, NT reverted: r11 -23us
// regression) + bucket-first CSR build.
// agg invariant (r4..r11): divergent-gather service rate is ~42G 64B-line-
// requests/s device-wide, independent of bytes/instr-count/depth/NT. agg at
// 1.6M lines/layer ~= 38us is AT that wall; fp8 (1 line/edge) fails the
// error budget. CSR build restructured to avoid N-scale passes and E-scale
// global atomics:
//   memset(196B) -> cnt (LDS bucket hist) -> scan196 (bases+init) ->
//   binA (reorder, unchanged) -> binC (per-bucket rowptr+dinv+csr place)
//   -> [mm -> agg]x3 -> pool -> head        (13 dispatches)
// ---------------------------------------------------------------------------

typedef _Float16 h8 __attribute__((ext_vector_type(8)));
typedef _Float16 half8 __attribute__((ext_vector_type(8)));

// --- cnt: per-bucket edge counts (bucket = dst>>8), LDS hist + merge --------
__global__ __launch_bounds__(256) void cnt_kernel(const int* __restrict__ dst,
                                                  int* __restrict__ bucket_hist, int E) {
  __shared__ int h[256];
  const int t = threadIdx.x;
  h[t] = 0;
  __syncthreads();
  for (int e = blockIdx.x * 256 + t; e < E; e += gridDim.x * 256)
    atomicAdd(&h[dst[e] >> 8], 1);
  __syncthreads();
  if (h[t]) atomicAdd(&bucket_hist[t], h[t]);
}

// --- scan196: bucket bases; also rowptr[n]=E and psum/pmax init -------------
__global__ __launch_bounds__(256) void scan196_kernel(const int* __restrict__ bucket_hist,
                                                      int* __restrict__ bkt_cur,
                                                      int* __restrict__ bkt_base,
                                                      int* __restrict__ rowptr,
                                                      float* __restrict__ psum,
                                                      unsigned int* __restrict__ pmax,
                                                      int nb, int n, int E) {
  __shared__ int s[256];
  const int t = threadIdx.x;
  int v = (t < nb) ? bucket_hist[t] : 0;
  s[t] = v;
  __syncthreads();
  for (int off = 1; off < 256; off <<= 1) {
    int x = (t >= off) ? s[t - off] : 0;
    __syncthreads();
    s[t] += x;
    __syncthreads();
  }
  int base = s[t] - v;  // exclusive
  if (t < nb) {
    bkt_cur[t] = base;
    bkt_base[t] = base;
  }
  if (t == nb) bkt_base[nb] = E;  // nb < 256 guaranteed (196)
  if (t == 0) rowptr[n] = E;
  if (t < 64) {
    psum[t] = 0.0f;
    pmax[t] = 0u;
  }
}

// --- binA: bucket-sort edges by dst>>8, packed (src<<8)|(dst&255) -----------
__global__ __launch_bounds__(256) void binA_kernel(const int* __restrict__ src,
                                                   const int* __restrict__ dst,
                                                   int* __restrict__ bkt_cur,
                                                   int* __restrict__ binned, int E) {
  __shared__ int hist[256];
  __shared__ int scan[256];
  __shared__ int delta[256];
  __shared__ int lcur[256];
  __shared__ int sorted[4096];
  __shared__ unsigned char bkt_of[4096];
  const int t = threadIdx.x;
  hist[t] = 0;
  __syncthreads();
  const int e0 = blockIdx.x * 4096;
  int pk[16];
  int bk[16];
#pragma unroll
  for (int i = 0; i < 16; ++i) {
    int e = e0 + t + 256 * i;  // coalesced
    if (e < E) {
      int s_ = src[e], d_ = dst[e];
      int b = d_ >> 8;
      pk[i] = (s_ << 8) | (d_ & 255);
      bk[i] = b;
      atomicAdd(&hist[b], 1);
    } else {
      bk[i] = -1;
    }
  }
  __syncthreads();
  int v = hist[t];
  scan[t] = v;
  __syncthreads();
  for (int off = 1; off < 256; off <<= 1) {
    int x = (t >= off) ? scan[t - off] : 0;
    __syncthreads();
    scan[t] += x;
    __syncthreads();
  }
  int excl = scan[t] - v;
  int g = (v > 0) ? atomicAdd(&bkt_cur[t], v) : 0;  // reserve global space
  delta[t] = g - excl;
  lcur[t] = excl;
  __syncthreads();
#pragma unroll
  for (int i = 0; i < 16; ++i) {
    if (bk[i] >= 0) {
      int p = atomicAdd(&lcur[bk[i]], 1);
      sorted[p] = pk[i];
      bkt_of[p] = (unsigned char)bk[i];
    }
  }
  __syncthreads();
  const int tot = scan[255];
  for (int i = t; i < tot; i += 256)  // coalesced run writes
    binned[delta[bkt_of[i]] + i] = sorted[i];
}

// --- binC: per-bucket rowptr + dinv + CSR placement (replaces scans+binB) ---
__global__ __launch_bounds__(256) void binC_kernel(const int* __restrict__ bkt_base,
                                                   const int* __restrict__ binned,
                                                   int* __restrict__ rowptr,
                                                   float* __restrict__ dinv,
                                                   int* __restrict__ csr_src, int n) {
  __shared__ int lh[256];
  __shared__ int ls[256];
  __shared__ int lcur[256];
  const int t = threadIdx.x;
  const int b = blockIdx.x;
  const int base = bkt_base[b];
  const int cnt = bkt_base[b + 1] - base;
  lh[t] = 0;
  __syncthreads();
  for (int i = t; i < cnt; i += 256) atomicAdd(&lh[binned[base + i] & 255], 1);
  __syncthreads();
  const int deg = lh[t];
  ls[t] = deg;
  __syncthreads();
  for (int off = 1; off < 256; off <<= 1) {
    int x = (t >= off) ? ls[t - off] : 0;
    __syncthreads();
    ls[t] += x;
    __syncthreads();
  }
  const int excl = ls[t] - deg;
  const int node = (b << 8) + t;
  if (node < n) {
    rowptr[node] = base + excl;
    dinv[node] = 1.0f / sqrtf((float)deg + 1.0f);
  }
  lcur[t] = excl;
  __syncthreads();
  for (int i = t; i < cnt; i += 256) {
    int e = binned[base + i];               // coalesced read (L2-hot)
    int p = atomicAdd(&lcur[e & 255], 1);   // LDS cursor
    csr_src[base + p] = e >> 8;             // scatter within 16KB window
  }
}

// --- dense matmul C[N,64] = fp16( dinv[row] * (A[N,K] @ W[K,64]) ) ----------
template <int K>
__global__ __launch_bounds__(256) void mm_kernel(const float* __restrict__ A,
                                                 const float* __restrict__ W,
                                                 const float* __restrict__ dinv,
                                                 _Float16* __restrict__ C, int nrows) {
  __shared__ float As[64 * K];
  const int t = threadIdx.x;
  const int lane = t & 63;
  const int wid = __builtin_amdgcn_readfirstlane(t >> 6);
  const int row0 = blockIdx.x * 64;

  constexpr int F4_PER_ROW = K / 4;
  constexpr int ROW_SHIFT = (K == 128) ? 5 : 4;
#pragma unroll
  for (int i = 0; i < K / 16; ++i) {
    int e4 = t + 256 * i;
    int r = e4 >> ROW_SHIFT;
    int k = (e4 & (F4_PER_ROW - 1)) * 4;
    int rc = row0 + r;
    if (rc > nrows - 1) rc = nrows - 1;
    float4 v = *(const float4*)(A + (size_t)rc * K + k);
    int s = r & 31;
    As[r * K + ((k + 0) ^ s)] = v.x;
    As[r * K + ((k + 1) ^ s)] = v.y;
    As[r * K + ((k + 2) ^ s)] = v.z;
    As[r * K + ((k + 3) ^ s)] = v.w;
  }
  __syncthreads();

  const int colbase = wid * 16;
  const float* Wc = W + colbase;
  float acc[16];
#pragma unroll
  for (int j = 0; j < 16; ++j) acc[j] = 0.0f;
  const int sw = lane & 31;
  const float* Arow = As + lane * K;

#pragma unroll 8
  for (int k = 0; k < K; ++k) {
    float a = Arow[k ^ sw];
    const float* Wk = Wc + k * 64;
#pragma unroll
    for (int j = 0; j < 16; ++j) acc[j] = fmaf(a, Wk[j], acc[j]);
  }

  int row = row0 + lane;
  if (row < nrows) {
    float dv = dinv[row];
    _Float16* Crow = C + (size_t)row * 64 + colbase;
    half8 o0, o1;
#pragma unroll
    for (int q = 0; q < 8; ++q) o0[q] = (_Float16)(dv * acc[q]);
#pragma unroll
    for (int q = 0; q < 8; ++q) o1[q] = (_Float16)(dv * acc[8 + q]);
    *(half8*)(Crow + 0) = o0;
    *(half8*)(Crow + 8) = o1;
  }
}

// --- agg v10 (plain loads): 8 edges per gather instruction ------------------
__global__ __launch_bounds__(256) void agg_kernel(const _Float16* __restrict__ hp,
                                                  const int* __restrict__ rowptr,
                                                  const int* __restrict__ csr_src,
                                                  const float* __restrict__ dinv,
                                                  const float* __restrict__ bias,
                                                  float* __restrict__ out, int n) {
  const int t = threadIdx.x;
  const int lane = t & 63;
  const int g = lane >> 3;
  const int s = lane & 7;
  const int wid = __builtin_amdgcn_readfirstlane(t >> 6);
  const int node = blockIdx.x * 4 + wid;   // wave-uniform
  if (node >= n) return;
  const int rbeg = rowptr[node];           // s_load
  const int rend = rowptr[node + 1];
  const int deg = rend - rbeg;
  const int nbf = deg >> 3;
  const int rem = deg & 7;

  float a0, a1, a2, a3, a4, a5, a6, a7;
  {  // self term: counted once (slot-0 lanes only)
    h8 v = *(const h8*)(hp + ((size_t)node << 6) + (s << 3));
    float m = (g == 0) ? 1.0f : 0.0f;
    a0 = m * (float)v[0]; a1 = m * (float)v[1];
    a2 = m * (float)v[2]; a3 = m * (float)v[3];
    a4 = m * (float)v[4]; a5 = m * (float)v[5];
    a6 = m * (float)v[6]; a7 = m * (float)v[7];
  }

  int j = rbeg;
#pragma unroll 2
  for (int b = 0; b < nbf; ++b, j += 8) {
    int i0 = csr_src[j + 0], i1 = csr_src[j + 1], i2 = csr_src[j + 2], i3 = csr_src[j + 3];
    int i4 = csr_src[j + 4], i5 = csr_src[j + 5], i6 = csr_src[j + 6], i7 = csr_src[j + 7];
    int idx = (g & 4) ? ((g & 2) ? ((g & 1) ? i7 : i6) : ((g & 1) ? i5 : i4))
                      : ((g & 2) ? ((g & 1) ? i3 : i2) : ((g & 1) ? i1 : i0));
    h8 v = *(const h8*)(hp + ((size_t)idx << 6) + (s << 3));  // 1 gather / 8 edges
    a0 += (float)v[0]; a1 += (float)v[1];
    a2 += (float)v[2]; a3 += (float)v[3];
    a4 += (float)v[4]; a5 += (float)v[5];
    a6 += (float)v[6]; a7 += (float)v[7];
  }
  if (rem) {
    int i0 = csr_src[j + 0];
    int i1 = (rem > 1) ? csr_src[j + 1] : i0;
    int i2 = (rem > 2) ? csr_src[j + 2] : i0;
    int i3 = (rem > 3) ? csr_src[j + 3] : i0;
    int i4 = (rem > 4) ? csr_src[j + 4] : i0;
    int i5 = (rem > 5) ? csr_src[j + 5] : i0;
    int i6 = (rem > 6) ? csr_src[j + 6] : i0;
    int idx = (g & 4) ? ((g & 2) ? ((g & 1) ? i0 : i6) : ((g & 1) ? i5 : i4))
                      : ((g & 2) ? ((g & 1) ? i3 : i2) : ((g & 1) ? i1 : i0));
    h8 v = *(const h8*)(hp + ((size_t)idx << 6) + (s << 3));
    float w = (g < rem) ? 1.0f : 0.0f;
    a0 = fmaf(w, (float)v[0], a0); a1 = fmaf(w, (float)v[1], a1);
    a2 = fmaf(w, (float)v[2], a2); a3 = fmaf(w, (float)v[3], a3);
    a4 = fmaf(w, (float)v[4], a4); a5 = fmaf(w, (float)v[5], a5);
    a6 = fmaf(w, (float)v[6], a6); a7 = fmaf(w, (float)v[7], a7);
  }

  // reduce across the 8 edge-slot groups (lanes s, s+8, ..., s+56)
  a0 += __shfl_xor(a0, 8); a0 += __shfl_xor(a0, 16); a0 += __shfl_xor(a0, 32);
  a1 += __shfl_xor(a1, 8); a1 += __shfl_xor(a1, 16); a1 += __shfl_xor(a1, 32);
  a2 += __shfl_xor(a2, 8); a2 += __shfl_xor(a2, 16); a2 += __shfl_xor(a2, 32);
  a3 += __shfl_xor(a3, 8); a3 += __shfl_xor(a3, 16); a3 += __shfl_xor(a3, 32);
  a4 += __shfl_xor(a4, 8); a4 += __shfl_xor(a4, 16); a4 += __shfl_xor(a4, 32);
  a5 += __shfl_xor(a5, 8); a5 += __shfl_xor(a5, 16); a5 += __shfl_xor(a5, 32);
  a6 += __shfl_xor(a6, 8); a6 += __shfl_xor(a6, 16); a6 += __shfl_xor(a6, 32);
  a7 += __shfl_xor(a7, 8); a7 += __shfl_xor(a7, 16); a7 += __shfl_xor(a7, 32);

  if (g == 0) {
    const float dv = dinv[node];
    const float* bp = bias + (s << 3);
    float4 b0 = *(const float4*)(bp + 0);
    float4 b1 = *(const float4*)(bp + 4);
    float4 r0, r1;
    r0.x = fmaxf(fmaf(dv, a0, b0.x), 0.0f);
    r0.y = fmaxf(fmaf(dv, a1, b0.y), 0.0f);
    r0.z = fmaxf(fmaf(dv, a2, b0.z), 0.0f);
    r0.w = fmaxf(fmaf(dv, a3, b0.w), 0.0f);
    r1.x = fmaxf(fmaf(dv, a4, b1.x), 0.0f);
    r1.y = fmaxf(fmaf(dv, a5, b1.y), 0.0f);
    r1.z = fmaxf(fmaf(dv, a6, b1.z), 0.0f);
    r1.w = fmaxf(fmaf(dv, a7, b1.w), 0.0f);
    float* op = out + ((size_t)node << 6) + (s << 3);
    *(float4*)(op + 0) = r0;
    *(float4*)(op + 4) = r1;
  }
}

// --- pooling: 256 blocks (atomic depth 256), unroll-4 independent loads -----
__global__ __launch_bounds__(256) void pool_kernel(const float* __restrict__ gbuf,
                                                   float* __restrict__ psum,
                                                   unsigned int* __restrict__ pmax, int n) {
  __shared__ float ls[4][64];
  __shared__ float lm[4][64];
  const int lane = threadIdx.x & 63;
  const int wid = threadIdx.x >> 6;
  const int stride = 256 * 4;  // wave-slots
  float s = 0.0f, m = 0.0f;    // post-relu values >= 0
  for (int base = blockIdx.x * 4 + wid; base < n; base += 4 * stride) {
#pragma unroll
    for (int k = 0; k < 4; ++k) {  // 4 independent loads in flight
      int node = base + k * stride;
      if (node < n) {
        float v = gbuf[((size_t)node << 6) + lane];
        s += v;
        m = fmaxf(m, v);
      }
    }
  }
  ls[wid][lane] = s;
  lm[wid][lane] = m;
  __syncthreads();
  if (wid == 0) {
    for (int w = 1; w < 4; ++w) {
      s += ls[w][lane];
      m = fmaxf(m, lm[w][lane]);
    }
    atomicAdd(&psum[lane], s);
    atomicMax(&pmax[lane], __float_as_uint(m));
  }
}

// --- MLP head ---------------------------------------------------------------
__global__ __launch_bounds__(64) void head_kernel(const float* __restrict__ psum,
                                                  const float* __restrict__ pmaxf,
                                                  const float* __restrict__ fw1,
                                                  const float* __restrict__ fb1,
                                                  const float* __restrict__ fw2,
                                                  const float* __restrict__ fb2,
                                                  float* __restrict__ out, float invN) {
  int lane = threadIdx.x;
  float acc = fb1[lane];
#pragma unroll 4
  for (int k = 0; k < 64; ++k)
    acc = fmaf(psum[k] * invN, fw1[k * 64 + lane], acc);
#pragma unroll 4
  for (int k = 0; k < 64; ++k)
    acc = fmaf(pmaxf[k], fw1[(64 + k) * 64 + lane], acc);
  float a = fmaxf(acc, 0.0f) * fw2[lane];
  for (int off = 32; off > 0; off >>= 1) a += __shfl_down(a, off);
  if (lane == 0) out[0] = a + fb2[0];
}

extern "C" void kernel_launch(void* const* d_in, const int* in_sizes, int n_in,
                              void* d_out, int out_size, void* d_ws, size_t ws_size,
                              hipStream_t stream) {
  const float* x   = (const float*)d_in[0];
  const int*   ei  = (const int*)d_in[1];
  const float* W1  = (const float*)d_in[2];
  const float* b1  = (const float*)d_in[3];
  const float* W2  = (const float*)d_in[4];
  const float* b2  = (const float*)d_in[5];
  const float* W3  = (const float*)d_in[6];
  const float* b3  = (const float*)d_in[7];
  const float* fw1 = (const float*)d_in[8];
  const float* fb1 = (const float*)d_in[9];
  const float* fw2 = (const float*)d_in[10];
  const float* fb2 = (const float*)d_in[11];
  float* out = (float*)d_out;

  const int N = in_sizes[0] / 128;  // 50000
  const int E = in_sizes[1] / 2;    // 800000
  const int* src = ei;
  const int* dst = ei + E;

  char* ws = (char*)d_ws;
  size_t off = 0;
  auto alloc = [&](size_t bytes) -> char* {
    char* p = ws + off;
    off = (off + bytes + 255) & ~(size_t)255;
    return p;
  };
  float*        dinv     = (float*)alloc((size_t)N * 4);
  int*          rowptr   = (int*)alloc((size_t)(N + 1) * 4);
  int*          bhist    = (int*)alloc(256 * 4);
  int*          bkt_cur  = (int*)alloc(256 * 4);
  int*          bkt_base = (int*)alloc(257 * 4);
  int*          binned   = (int*)alloc((size_t)E * 4 + 64);
  int*          csr_src  = (int*)alloc((size_t)E * 4 + 64);  // pad: safe overread
  _Float16*     bufA     = (_Float16*)alloc((size_t)N * 64 * 2);
  float*        bufB     = (float*)alloc((size_t)N * 64 * 4);
  float*        psum     = (float*)alloc(64 * 4);
  unsigned int* pmax     = (unsigned int*)alloc(64 * 4);

  const int mmBlk  = (N + 63) / 64;
  const int aggBlk = (N + 3) / 4;        // 1 node per wave
  const int NB     = (N + 255) / 256;    // 196 buckets
  const int binBlk = (E + 4095) / 4096;  // 196 tiles

  hipMemsetAsync(bhist, 0, 256 * 4, stream);
  cnt_kernel<<<128, 256, 0, stream>>>(dst, bhist, E);
  scan196_kernel<<<1, 256, 0, stream>>>(bhist, bkt_cur, bkt_base, rowptr, psum, pmax,
                                        NB, N, E);
  binA_kernel<<<binBlk, 256, 0, stream>>>(src, dst, bkt_cur, binned, E);
  binC_kernel<<<NB, 256, 0, stream>>>(bkt_base, binned, rowptr, dinv, csr_src, N);

  // layer 1
  mm_kernel<128><<<mmBlk, 256, 0, stream>>>(x, W1, dinv, bufA, N);
  agg_kernel<<<aggBlk, 256, 0, stream>>>(bufA, rowptr, csr_src, dinv, b1, bufB, N);
  // layer 2
  mm_kernel<64><<<mmBlk, 256, 0, stream>>>(bufB, W2, dinv, bufA, N);
  agg_kernel<<<aggBlk, 256, 0, stream>>>(bufA, rowptr, csr_src, dinv, b2, bufB, N);
  // layer 3
  mm_kernel<64><<<mmBlk, 256, 0, stream>>>(bufB, W3, dinv, bufA, N);
  agg_kernel<<<aggBlk, 256, 0, stream>>>(bufA, rowptr, csr_src, dinv, b3, bufB, N);

  pool_kernel<<<256, 256, 0, stream>>>(bufB, psum, pmax, N);
  head_kernel<<<1, 64, 0, stream>>>(psum, (const float*)pmax, fw1, fb1, fw2, fb2, out,
                                    1.0f / (float)N);
}